// Round 10
// baseline (418.952 us; speedup 1.0000x reference)
//
#include <hip/hip_runtime.h>

// Problem constants (SpeakerAwareCTC): B=16, T=1000, D=512, V=5000, U=64, S=2U+1=129
#define NB 16
#define NT 1000
#define ND 512
#define NV 5000
#define NVP 5120          // WT padded rows (zeros beyond 5000)
#define NU 64
#define NLL 72            // ll row stride (u-major rows, 65 used)
#define NM (NB * NT)      // 16000 flattened rows
#define NCH2 20           // N-chunks of 256 cols (k_denom)

typedef short short8v __attribute__((ext_vector_type(8)));
typedef float float4v __attribute__((ext_vector_type(4)));

#define NEGINF (-__builtin_inff())
#define SENTL  (-1.0e30f)   // finite "-inf": exp2(SENTL - m) == 0 for any sane m
#define LOG2E 1.4426950408889634f
#define LN2F  0.6931471805599453f
// reference sentinel: -2001 + logf(expf(1)-1) = -2000.4586751f (natural), in base-2:
#define SENT2 (-2000.4586751f * LOG2E)

__device__ __forceinline__ float fexp2(float x) { return __builtin_amdgcn_exp2f(x); }
__device__ __forceinline__ float flog2(float x) { return __builtin_amdgcn_logf(x); }

// DPP lane shifts (VALU-latency; serial-chain friendly)
__device__ __forceinline__ float dpp_shr1(float x) {  // lane i <- lane i-1
  int xi = __builtin_bit_cast(int, x);
  int r = __builtin_amdgcn_update_dpp(xi, xi, 0x138, 0xf, 0xf, false);
  return __builtin_bit_cast(float, r);
}
__device__ __forceinline__ float dpp_shl1(float x) {  // lane i <- lane i+1
  int xi = __builtin_bit_cast(int, x);
  int r = __builtin_amdgcn_update_dpp(xi, xi, 0x130, 0xf, 0xf, false);
  return __builtin_bit_cast(float, r);
}

__device__ __forceinline__ short f2bf(float x) {
  unsigned int u = __builtin_bit_cast(unsigned int, x);
  unsigned int r = (u + 0x7fffu + ((u >> 16) & 1u)) >> 16;
  return (short)(unsigned short)r;
}
__device__ __forceinline__ float bf2f(short h) {
  unsigned int u = ((unsigned int)(unsigned short)h) << 16;
  return __builtin_bit_cast(float, u);
}

// async global->LDS, 16B per lane; LDS dest = wave-uniform base + lane*16
__device__ __forceinline__ void g2lds16(const short* g, short* l) {
  __builtin_amdgcn_global_load_lds(
      (const __attribute__((address_space(1))) void*)g,
      (__attribute__((address_space(3))) void*)l, 16, 0, 0);
}

// base-2 logaddexp on sentinel-finite values
__device__ __forceinline__ float lae2s(float a, float b) {
  float m = fmaxf(a, b);
  return m + flog2(fexp2(a - m) + fexp2(b - m));
}
__device__ __forceinline__ float lae3s(float a, float b, float c) {
  float m = fmaxf(fmaxf(a, b), c);
  return m + flog2(fexp2(a - m) + fexp2(b - m) + fexp2(c - m));
}
// base-2 port of reference log_substraction_exp (finite-sentinel inputs)
__device__ __forceinline__ float lsub2(float a, float b) {
  float tmp = b + flog2(fexp2(a - b) - 1.0f);
  if (__builtin_isinf(tmp)) tmp = SENT2;
  return tmp;
}

// ---------------- kernel 0: zero the scalar output -------------------------
__global__ void k_zero(float* out) {
  if (threadIdx.x == 0) out[0] = 0.0f;
}

// ---------------- kernel 1: hs f32 -> bf16, granule-swizzled ---------------
__global__ __launch_bounds__(256) void k_cvt_hs(const float* __restrict__ in,
                                                short* __restrict__ out) {
  size_t i = (size_t)blockIdx.x * 256 + threadIdx.x;  // granule id, 1,024,000 total
  const float4* p = (const float4*)in + i * 2;
  float4 v0 = p[0], v1 = p[1];
  short8v r;
  r[0] = f2bf(v0.x); r[1] = f2bf(v0.y); r[2] = f2bf(v0.z); r[3] = f2bf(v0.w);
  r[4] = f2bf(v1.x); r[5] = f2bf(v1.y); r[6] = f2bf(v1.z); r[7] = f2bf(v1.w);
  int row = (int)(i >> 6);        // 64 granules per 512-col row
  int g = (int)(i & 63);
  int gs = (g & ~7) | ((g & 7) ^ (row & 7));
  *(short8v*)(out + (size_t)row * ND + gs * 8) = r;
}

// ------- kernel 2: W [512][5000] f32 -> WT/WTlo [5120][512] bf16 -----------
// transposed, granule-swizzled rows; hi = bf16(w), lo = bf16(w - hi).
__global__ __launch_bounds__(256) void k_cvt_wt(const float* __restrict__ W,
                                                short* __restrict__ WT,
                                                short* __restrict__ WTlo) {
  __shared__ short tileH[64 * 72];
  __shared__ short tileL[64 * 72];
  int n0 = blockIdx.x * 64, k0 = blockIdx.y * 64;
  int tid = threadIdx.x;
  int kr = tid >> 2, part = tid & 3;
  const float* src = W + (size_t)(k0 + kr) * NV + n0 + part * 16;
#pragma unroll
  for (int jj = 0; jj < 4; ++jj) {
    int c = n0 + part * 16 + jj * 4;
    float4 v;
    if (c + 3 < NV) {
      v = *(const float4*)(src + jj * 4);
    } else {
      v.x = (c + 0 < NV) ? src[jj * 4 + 0] : 0.f;
      v.y = (c + 1 < NV) ? src[jj * 4 + 1] : 0.f;
      v.z = (c + 2 < NV) ? src[jj * 4 + 2] : 0.f;
      v.w = (c + 3 < NV) ? src[jj * 4 + 3] : 0.f;
    }
    int base = kr * 72 + part * 16 + jj * 4;
    float vv[4] = {v.x, v.y, v.z, v.w};
#pragma unroll
    for (int q = 0; q < 4; ++q) {
      short h = f2bf(vv[q]);
      tileH[base + q] = h;
      tileL[base + q] = f2bf(vv[q] - bf2f(h));
    }
  }
  __syncthreads();
  int n = tid & 63, kq = tid >> 6;
  int nn = n0 + n;
  if (nn < NVP) {
#pragma unroll
    for (int half = 0; half < 2; ++half) {
      short8v vh, vl;
#pragma unroll
      for (int jj = 0; jj < 8; ++jj) {
        vh[jj] = tileH[(kq * 16 + half * 8 + jj) * 72 + n];
        vl[jj] = tileL[(kq * 16 + half * 8 + jj) * 72 + n];
      }
      int g = (k0 >> 3) + kq * 2 + half;
      int gs = (g & ~7) | ((g & 7) ^ (nn & 7));
      *(short8v*)(WT + (size_t)nn * ND + gs * 8) = vh;
      *(short8v*)(WTlo + (size_t)nn * ND + gs * 8) = vl;
    }
  }
}

// -------- kernel 3: gather Wg_hi/lo[b][u][k] from WT/WTlo rows (coalesced) -
__global__ __launch_bounds__(64) void k_gather2(const short* __restrict__ WT,
                                                const short* __restrict__ WTlo,
                                                const int* __restrict__ ys,
                                                short* __restrict__ Wg_hi,
                                                short* __restrict__ Wg_lo) {
  int u = blockIdx.x, b = blockIdx.y, t = threadIdx.x;  // t = logical granule
  short8v hi = {0,0,0,0,0,0,0,0}, lo = {0,0,0,0,0,0,0,0};
  if (u < NU + 1) {
    int lab = (u == 0) ? 0 : ys[b * NU + u - 1];
    int ps = (t & ~7) | ((t & 7) ^ (lab & 7));
    hi = *(const short8v*)(WT + (size_t)lab * ND + ps * 8);
    lo = *(const short8v*)(WTlo + (size_t)lab * ND + ps * 8);
  }
  int q = (t & ~7) | ((t & 7) ^ (u & 7));
  size_t base = ((size_t)(b * 128 + u)) * ND + q * 8;
  *(short8v*)(Wg_hi + base) = hi;
  *(short8v*)(Wg_lo + base) = lo;
}

// -------- kernel 4: ll[b][u][t] = hs[b,t,:] . W[:,lab(u)] + bias -----------
// batched MFMA GEMM, TRANSPOSED output (u-major rows, stride NLL).
__global__ __launch_bounds__(256) void k_labg(const short* __restrict__ hsb,
                                              const short* __restrict__ Wg_hi,
                                              const short* __restrict__ Wg_lo,
                                              const int* __restrict__ ys,
                                              const float* __restrict__ bias,
                                              float* __restrict__ ll) {
  __shared__ short As[128 * 64];
  __shared__ short Bh[128 * 64];
  __shared__ short Bl[128 * 64];

  int mt = blockIdx.x, b = blockIdx.y;
  int t0 = mt * 128;
  int tid = threadIdx.x;
  int lane = tid & 63, wave = tid >> 6;
  int wm = wave >> 1, wn = wave & 1;
  int lrow = lane & 15, lkhi = lane >> 4;

  const short* gaBase = hsb + (size_t)(b * NT + t0 + wave * 32 + (lane >> 3)) * ND + (lane & 7) * 8;
  const short* ghBase = Wg_hi + (size_t)(b * 128 + wave * 32 + (lane >> 3)) * ND + (lane & 7) * 8;
  const short* glBase = Wg_lo + (size_t)(b * 128 + wave * 32 + (lane >> 3)) * ND + (lane & 7) * 8;

  float4v acc[4][4];
#pragma unroll
  for (int m = 0; m < 4; ++m)
#pragma unroll
    for (int n = 0; n < 4; ++n)
#pragma unroll
      for (int j = 0; j < 4; ++j) acc[m][n][j] = 0.f;

  for (int s = 0; s < 8; ++s) {
    int k0 = s * 64;
#pragma unroll
    for (int i = 0; i < 4; ++i) {
      g2lds16(gaBase + (size_t)(i * 8) * ND + k0, &As[(wave * 32 + i * 8) * 64]);
      g2lds16(ghBase + (size_t)(i * 8) * ND + k0, &Bh[(wave * 32 + i * 8) * 64]);
      g2lds16(glBase + (size_t)(i * 8) * ND + k0, &Bl[(wave * 32 + i * 8) * 64]);
    }
    __syncthreads();
#pragma unroll
    for (int kk = 0; kk < 2; ++kk) {
      short8v av[4], bhv[4], blv2[4];
#pragma unroll
      for (int m = 0; m < 4; ++m) {
        int r = wm * 64 + m * 16 + lrow;
        int col = (kk * 32 + lkhi * 8) ^ ((r & 7) << 3);
        av[m] = *(const short8v*)&As[r * 64 + col];
      }
#pragma unroll
      for (int n = 0; n < 4; ++n) {
        int r = wn * 64 + n * 16 + lrow;
        int col = (kk * 32 + lkhi * 8) ^ ((r & 7) << 3);
        bhv[n] = *(const short8v*)&Bh[r * 64 + col];
        blv2[n] = *(const short8v*)&Bl[r * 64 + col];
      }
#pragma unroll
      for (int m = 0; m < 4; ++m)
#pragma unroll
        for (int n = 0; n < 4; ++n) {
          acc[m][n] = __builtin_amdgcn_mfma_f32_16x16x32_bf16(av[m], bhv[n], acc[m][n], 0, 0, 0);
          acc[m][n] = __builtin_amdgcn_mfma_f32_16x16x32_bf16(av[m], blv2[n], acc[m][n], 0, 0, 0);
        }
    }
    __syncthreads();
  }

  // epilogue: bias per u-row; TRANSPOSED write ll[(b*NLL+u)*NT + t]
  float bu[4]; bool uval[4];
#pragma unroll
  for (int n = 0; n < 4; ++n) {
    int u = wn * 64 + n * 16 + lrow;
    uval[n] = u < NU + 1;
    int lab = (u == 0) ? 0 : (uval[n] ? ys[b * NU + u - 1] : 0);
    bu[n] = uval[n] ? bias[lab] : 0.f;
  }
#pragma unroll
  for (int m = 0; m < 4; ++m)
#pragma unroll
    for (int j = 0; j < 4; ++j) {
      int trow = t0 + wm * 64 + m * 16 + lkhi * 4 + j;
      if (trow < NT) {
#pragma unroll
        for (int n = 0; n < 4; ++n) {
          int u = wn * 64 + n * 16 + lrow;
          if (uval[n])
            ll[((size_t)(b * NLL + u)) * NT + trow] = acc[m][n][j] + bu[n];
        }
      }
    }
}

// -------- kernel 5: per-chunk partial logsumexp of hs@W + b (bf16 MFMA) ----
// 128x256 block tile (2x2 waves, wave tile 64x128, acc[4][8]), BK=64,
// single-buffer LDS 48KB; bijective XCD swizzle + 8-mt superblocks.
__global__ __launch_bounds__(256) void k_denom(const short* __restrict__ hsb,
                                               const short* __restrict__ WT,
                                               const float* __restrict__ bias,
                                               float* __restrict__ pm,
                                               float* __restrict__ ps) {
  __shared__ short As[128 * 64];
  __shared__ short Bs[256 * 64];
  __shared__ float mred[128][2];
  __shared__ float sred[128][2];

  // bijective XCD swizzle for 2500 blocks (q=312, r=4)
  int lin = blockIdx.x;
  int xcd = lin & 7, j = lin >> 3;
  int o = xcd * 312 + ((xcd < 4) ? xcd : 4) + j;   // start_k = k*q + min(k,r)
  int mt, chunk;
  if (o < 2400) {                 // 15 superblocks x (8 mt x 20 ch)
    int sb = o / 160, w = o % 160;
    mt = sb * 8 + (w & 7);        // mloc fastest: concurrent blocks share hsb+WT
    chunk = w >> 3;
  } else {                        // tail: 5 mt x 20 ch
    int w = o - 2400;
    mt = 120 + (w % 5);
    chunk = w / 5;
  }
  int t0 = mt * 128;
  int n0 = chunk * 256;
  int tid = threadIdx.x;
  int lane = tid & 63, wave = tid >> 6;
  int wm = wave >> 1, wn = wave & 1;
  int lrow = lane & 15, lkhi = lane >> 4;

  const short* gaBase = hsb + (size_t)(t0 + wave * 32 + (lane >> 3)) * ND + (lane & 7) * 8;
  const short* gwBase = WT + (size_t)(n0 + wave * 64 + (lane >> 3)) * ND + (lane & 7) * 8;

  float4v acc[4][8];
#pragma unroll
  for (int m = 0; m < 4; ++m)
#pragma unroll
    for (int n = 0; n < 8; ++n)
#pragma unroll
      for (int j2 = 0; j2 < 4; ++j2) acc[m][n][j2] = 0.f;

  auto stage = [&](int s) {
    int k0 = s * 64;
#pragma unroll
    for (int i = 0; i < 4; ++i)
      g2lds16(gaBase + (size_t)(i * 8) * ND + k0, &As[(wave * 32 + i * 8) * 64]);
#pragma unroll
    for (int i = 0; i < 8; ++i)
      g2lds16(gwBase + (size_t)(i * 8) * ND + k0, &Bs[(wave * 64 + i * 8) * 64]);
  };
  auto compute = [&]() {
#pragma unroll
    for (int kk = 0; kk < 2; ++kk) {
      short8v av[4], wv[8];
#pragma unroll
      for (int m = 0; m < 4; ++m) {
        int r = wm * 64 + m * 16 + lrow;
        int col = (kk * 32 + lkhi * 8) ^ ((r & 7) << 3);
        av[m] = *(const short8v*)&As[r * 64 + col];
      }
#pragma unroll
      for (int n = 0; n < 8; ++n) {
        int r = wn * 128 + n * 16 + lrow;
        int col = (kk * 32 + lkhi * 8) ^ ((r & 7) << 3);
        wv[n] = *(const short8v*)&Bs[r * 64 + col];
      }
#pragma unroll
      for (int m = 0; m < 4; ++m)
#pragma unroll
        for (int n = 0; n < 8; ++n)
          acc[m][n] = __builtin_amdgcn_mfma_f32_16x16x32_bf16(av[m], wv[n], acc[m][n], 0, 0, 0);
    }
  };

  for (int s = 0; s < 8; ++s) {
    stage(s);
    __syncthreads();
    compute();
    __syncthreads();
  }

  // epilogue: per-row (m,s) over this block's 256 cols (mask cols >= NV)
  float bcol[8]; bool cval[8];
#pragma unroll
  for (int n = 0; n < 8; ++n) {
    int c = n0 + wn * 128 + n * 16 + lrow;
    cval[n] = c < NV;
    bcol[n] = cval[n] ? bias[c] : 0.f;
  }
#pragma unroll
  for (int m = 0; m < 4; ++m)
#pragma unroll
    for (int j2 = 0; j2 < 4; ++j2) {
      float mx = NEGINF;
#pragma unroll
      for (int n = 0; n < 8; ++n) {
        float v = cval[n] ? acc[m][n][j2] + bcol[n] : NEGINF;
        mx = fmaxf(mx, v);
      }
#pragma unroll
      for (int d = 1; d < 16; d <<= 1) mx = fmaxf(mx, __shfl_xor(mx, d));
      float mxc = fmaxf(mx, -3.0e38f);   // NaN guard (all-invalid half-tile)
      float p = 0.f;
#pragma unroll
      for (int n = 0; n < 8; ++n) {
        float v = cval[n] ? acc[m][n][j2] + bcol[n] : NEGINF;
        p += __expf(v - mxc);
      }
#pragma unroll
      for (int d = 1; d < 16; d <<= 1) p += __shfl_xor(p, d);
      if (lrow == 0) {
        int rloc = wm * 64 + m * 16 + lkhi * 4 + j2;
        mred[rloc][wn] = mx;
        sred[rloc][wn] = p;
      }
    }
  __syncthreads();
  if (tid < 128) {
    int row = t0 + tid;
    float m0 = mred[tid][0], m1 = mred[tid][1];
    float m = fmaxf(m0, m1);
    float ss = 0.f;
    if (m != NEGINF)
      ss = ((m0 == NEGINF) ? 0.f : sred[tid][0] * __expf(m0 - m))
         + ((m1 == NEGINF) ? 0.f : sred[tid][1] * __expf(m1 - m));
    pm[(size_t)chunk * NM + row] = m;
    ps[(size_t)chunk * NM + row] = ss;
  }
}

// -------- kernel 5b: combine 20 chunk partials -> denom[row] ---------------
__global__ __launch_bounds__(256) void k_dred(const float* __restrict__ pm,
                                              const float* __restrict__ ps,
                                              float* __restrict__ denom) {
  int row = blockIdx.x * 256 + threadIdx.x;
  if (row >= NM) return;
  float m = NEGINF, s = 0.f;
  for (int c = 0; c < NCH2; ++c) {
    float mc = pm[(size_t)c * NM + row];
    float sc = ps[(size_t)c * NM + row];
    if (mc == NEGINF) continue;
    if (mc > m) { s = s * __expf(m - mc) + sc; m = mc; }
    else        { s += sc * __expf(mc - m); }
  }
  denom[row] = m + __logf(s);
}

// -------- kernel 6: fwd (blocks 0..15) || bwd (blocks 16..31) --------------
// ll is [b][u][t] u-major (stride NLL rows): lane reads its own t-row.
__global__ __launch_bounds__(64) void k_fwdbwd(const float* __restrict__ ll,
                                               const float* __restrict__ denom,
                                               const int* __restrict__ ys,
                                               float* __restrict__ aod,
                                               float* __restrict__ bp) {
  __shared__ float denS[NT];
  __shared__ float blkS[NT];
  int bid = blockIdx.x;
  int l = threadIdx.x;
  int b = (bid < NB) ? bid : bid - NB;
  const float* llb = ll + (size_t)b * NLL * NT;
  const float* denb = denom + b * NT;
#pragma unroll
  for (int i = 0; i < 16; ++i) {
    int idx = i * 64 + l;
    if (idx < NT) { denS[idx] = denb[idx]; blkS[idx] = llb[idx]; }  // row 0 = blank
  }
  __syncthreads();
  const float* lrow = llb + (size_t)(1 + l) * NT;   // this lane's label row

  if (bid < NB) {
    // ---------------- forward ----------------
    int lab = ys[b * NU + l];
    int labp = ys[b * NU + ((l >= 1) ? (l - 1) : 0)];
    bool skip = (l >= 1) && (lab != labp);
    float* aodb = aod + (size_t)b * NT * NU;

    float den = denS[0];
    float ae = (l == 0) ? (blkS[0] - den) * LOG2E : SENTL;
    float ao = (l == 0) ? (lrow[0] - den) * LOG2E : SENTL;
    aodb[l] = ao;

    float cl[16];
#pragma unroll
    for (int j = 0; j < 16; ++j) {
      int tt = 1 + j; if (tt > NT - 1) tt = NT - 1;
      cl[j] = lrow[tt];
    }
    for (int g = 0; g < 63; ++g) {
      float nl[16];
      if (g < 62) {
#pragma unroll
        for (int j = 0; j < 16; ++j) {
          int tt = 17 + g * 16 + j; if (tt > NT - 1) tt = NT - 1;
          nl[j] = lrow[tt];
        }
      } else {
#pragma unroll
        for (int j = 0; j < 16; ++j) nl[j] = 0.f;
      }
#pragma unroll
      for (int j = 0; j < 16; ++j) {
        int t = 1 + g * 16 + j;
        if (t < NT) {
          float d2 = denS[t];
          float pb = (blkS[t] - d2) * LOG2E, pl = (cl[j] - d2) * LOG2E;
          float po = dpp_shr1(ao); if (l == 0) po = SENTL;
          float aen = pb + lae2s(ae, po);
          float aon = pl + lae3s(ao, ae, skip ? po : SENTL);
          ae = aen; ao = aon;
          aodb[t * NU + l] = ao;
        }
      }
#pragma unroll
      for (int j = 0; j < 16; ++j) cl[j] = nl[j];
    }
  } else {
    // ---------------- backward ----------------
    int lab = ys[b * NU + l];
    int labn = ys[b * NU + ((l < NU - 1) ? (l + 1) : l)];
    bool skipn = (l < NU - 1) && (labn != lab);
    float* bpb = bp + (size_t)b * NT * NU;

    float bo = (l == NU - 1) ? 0.0f : SENTL;
    float be = SENTL;
    float b128 = 0.0f;
    bpb[(NT - 1) * NU + l] = bo;

    float blv[16];
#pragma unroll
    for (int j = 0; j < 16; ++j) {
      int tt = NT - 2 - j; if (tt < 0) tt = 0;
      blv[j] = lrow[tt + 1];
    }
    for (int g = 0; g < 63; ++g) {
      float nl2[16];
      if (g < 62) {
#pragma unroll
        for (int j = 0; j < 16; ++j) {
          int tt = NT - 2 - 16 * (g + 1) - j; if (tt < 0) tt = 0;
          nl2[j] = lrow[tt + 1];
        }
      } else {
#pragma unroll
        for (int j = 0; j < 16; ++j) nl2[j] = 0.f;
      }
#pragma unroll
      for (int j = 0; j < 16; ++j) {
        int t = NT - 2 - 16 * g - j;
        if (t >= 0) {
          float d2 = denS[t + 1];
          float pbv = (blkS[t + 1] - d2) * LOG2E, plv = (blv[j] - d2) * LOG2E;
          float me = pbv + be;
          float mo = plv + bo;
          float m128 = pbv + b128;
          float ne = dpp_shl1(me); if (l == NU - 1) ne = m128;
          float no = dpp_shl1(mo); if (l == NU - 1) no = SENTL;
          float ben = lae2s(me, mo);
          float bon = lae3s(mo, ne, skipn ? no : SENTL);
          bpb[t * NU + l] = lsub2(bon, mo);
          be = ben; bo = bon; b128 = m128;
        }
      }
#pragma unroll
      for (int j = 0; j < 16; ++j) blv[j] = nl2[j];
    }
  }
}

// -------- kernel 7: loss = mean_b( -sum_u lse_t(alpha+bp) / count ) --------
__global__ __launch_bounds__(512) void k_loss(const float* __restrict__ aod,
                                              const float* __restrict__ bp,
                                              const int* __restrict__ hlens,
                                              float* __restrict__ out) {
  __shared__ float ms[8][64], ss[8][64];
  int b = blockIdx.x, tid = threadIdx.x;
  int w = tid >> 6, l = tid & 63;
  const float* ab = aod + (size_t)b * NT * NU;
  const float* pb = bp + (size_t)b * NT * NU;
  float m = NEGINF, s = 0.f;
  int t0 = w * 125, t1 = t0 + 125;
  for (int t = t0; t < t1; ++t) {
    float x = ab[t * NU + l] + pb[t * NU + l];
    if (__builtin_isnan(x) || x < -1.0e29f) continue;   // sentinel == -inf
    if (x > m) { s = s * fexp2(m - x) + 1.0f; m = x; }
    else       { s += fexp2(x - m); }
  }
  ms[w][l] = m; ss[w][l] = s;
  __syncthreads();
  if (w == 0) {
    float mm = NEGINF;
#pragma unroll
    for (int i = 0; i < 8; ++i) mm = fmaxf(mm, ms[i][l]);
    float lu;
    if (mm == NEGINF) lu = NEGINF;
    else {
      float st = 0.f;
#pragma unroll
      for (int i = 0; i < 8; ++i)
        st += (ms[i][l] == NEGINF) ? 0.f : ss[i][l] * fexp2(ms[i][l] - mm);
      lu = (mm + flog2(st)) * LN2F;
    }
    bool msk = __builtin_isinf(lu);
    float sv = msk ? 0.f : lu;
    float cv = msk ? 0.f : 1.f;
#pragma unroll
    for (int d = 1; d < 64; d <<= 1) { sv += __shfl_xor(sv, d); cv += __shfl_xor(cv, d); }
    if (l == 0) {
      float lf = sv / cv;
      if (hlens[b] < NU) lf = 0.f;
      atomicAdd(out, -lf * (1.0f / NB));
    }
  }
}

// ---------------------------------------------------------------------------
extern "C" void kernel_launch(void* const* d_in, const int* in_sizes, int n_in,
                              void* d_out, int out_size, void* d_ws, size_t ws_size,
                              hipStream_t stream) {
  const float* hs    = (const float*)d_in[0];
  const int*   hlens = (const int*)d_in[1];
  const int*   ys    = (const int*)d_in[2];
  const float* W     = (const float*)d_in[4];
  const float* bias  = (const float*)d_in[5];
  float* out = (float*)d_out;

  char* ws = (char*)d_ws;
  short* hsb   = (short*)(ws + 0);           // 16,384,000 B  [16000][512] bf16 (swizzled)
  short* WT    = (short*)(ws + 16384000);    //  5,242,880 B  [5120][512] bf16 hi (swizzled)
  short* WTlo  = (short*)(ws + 21626880);    //  5,242,880 B  [5120][512] bf16 lo (swizzled)
  float* pm    = (float*)(ws + 26869760);    //  1,280,000 B  [20][16000]; dead after k_dred
  float* psv   = (float*)(ws + 28149760);    //  1,280,000 B
  float* dnm   = (float*)(ws + 29429760);    //     64,000 B
  float* ll    = (float*)(ws + 29493760);    //  4,608,000 B  [16][72][1000] f32 (end 34,101,760)
  // after k_dred: pm/psv dead -> Wg_hi/lo alias them
  short* Wg_hi = (short*)(ws + 26869760);    //  2,097,152 B  [16][128][512] bf16 (swizzled)
  short* Wg_lo = (short*)(ws + 28966912);    //  2,097,152 B  -> needs to end before ll? no: ends 31,064,064 > 29,493,760!
  // NOTE: Wg must not overlap ll. Place Wg in the WTlo region instead?
  // WTlo is still needed by k_gather2 itself. Use a dedicated slice after ll:
  // (re-point Wg_hi/lo below)

  // dedicated Wg region after ll:
  Wg_hi = (short*)(ws + 34101760);           //  2,097,152 B
  Wg_lo = (short*)(ws + 36198912);           //  2,097,152 B  (end 38,296,064)
  // after k_labg: hsb dead -> aod/bp alias it
  float* aod   = (float*)(ws + 0);           //  4,096,000 B
  float* bpb   = (float*)(ws + 4096000);     //  4,096,000 B

  k_zero<<<1, 64, 0, stream>>>(out);
  k_cvt_hs<<<4000, 256, 0, stream>>>(hs, hsb);
  k_cvt_wt<<<dim3(80, 8), 256, 0, stream>>>(W, WT, WTlo);
  k_denom<<<2500, 256, 0, stream>>>(hsb, WT, bias, pm, psv);
  k_dred<<<63, 256, 0, stream>>>(pm, psv, dnm);
  k_gather2<<<dim3(128, 16), 64, 0, stream>>>(WT, WTlo, ys, Wg_hi, Wg_lo);
  k_labg<<<dim3(8, 16), 256, 0, stream>>>(hsb, Wg_hi, Wg_lo, ys, bias, ll);
  k_fwdbwd<<<32, 64, 0, stream>>>(ll, dnm, ys, aod, bpb);
  k_loss<<<16, 512, 0, stream>>>(aod, bpb, hlens, out);
}